// Round 14
// baseline (835.194 us; speedup 1.0000x reference)
//
#include <hip/hip_runtime.h>
#include <math.h>

// ---- problem constants ----
#define NTOK 2048      // B*T
#define DD   128       // model dim D
#define NHEAD 4
#define DHEAD 32
#define NLAYER 4
#define NEXP 8
#define DHID 512
#define NVOCAB 50257
#define VPAD  50304    // 393*128
#define SEQ   256
#define NBATCH 8

typedef __attribute__((ext_vector_type(8))) short short8v;   // 8 bf16 in 4 VGPRs
typedef __attribute__((ext_vector_type(4))) float f32x4;

__device__ __forceinline__ unsigned short nm_bf16r(float f) {
  unsigned u = __float_as_uint(f);
  u += 0x7fffu + ((u >> 16) & 1u);          // RNE
  return (unsigned short)(u >> 16);
}

__device__ __forceinline__ float nm_silu(float a) {
  return a / (1.f + __expf(-a));
}

template<int N4>
__device__ __forceinline__ float nm_dotv(const float* __restrict__ a,
                                         const float* __restrict__ w) {
  const float4* a4 = (const float4*)a;
  const float4* w4 = (const float4*)w;
  float sx = 0.f, sy = 0.f, sz = 0.f, sw = 0.f;
#pragma unroll 16
  for (int k = 0; k < N4; ++k) {
    float4 av = a4[k], wv = w4[k];
    sx = fmaf(av.x, wv.x, sx);
    sy = fmaf(av.y, wv.y, sy);
    sz = fmaf(av.z, wv.z, sz);
    sw = fmaf(av.w, wv.w, sw);
  }
  return (sx + sy) + (sz + sw);
}

__device__ __forceinline__ short8v nm_cvt8(const float* p) {
  const float4* p4 = (const float4*)p;
  float4 a = p4[0], b = p4[1];
  short8v r;
  r[0] = (short)nm_bf16r(a.x); r[1] = (short)nm_bf16r(a.y);
  r[2] = (short)nm_bf16r(a.z); r[3] = (short)nm_bf16r(a.w);
  r[4] = (short)nm_bf16r(b.x); r[5] = (short)nm_bf16r(b.y);
  r[6] = (short)nm_bf16r(b.z); r[7] = (short)nm_bf16r(b.w);
  return r;
}

// ===================== fused init: layer-3 weight cvt + embed+LN1 + zero =====================
#define CW_W1  524288ull                        // 8*512*128
#define CW_ALL 1048576ull                       // + 8*128*512
#define CWB    1024                             // CW_ALL / 1024
__global__ __launch_bounds__(256) void nm_init(
    const int* __restrict__ idx, const float* __restrict__ tok,
    const float* __restrict__ pos, const float* __restrict__ g,
    const float* __restrict__ b,
    const float* __restrict__ w1l3, const float* __restrict__ w2l3,
    float* __restrict__ x, float* __restrict__ xl,
    unsigned short* __restrict__ w1b3, unsigned short* __restrict__ w2b3,
    int* __restrict__ zp) {
  int bid = blockIdx.x, tid = threadIdx.x;
  if (bid < CWB) {
    size_t base = ((size_t)bid * 256 + tid) * 4;
    if (base < CW_W1) {
      float4 v = *(const float4*)(w1l3 + base);
      ushort4 us = {nm_bf16r(v.x), nm_bf16r(v.y), nm_bf16r(v.z), nm_bf16r(v.w)};
      *(ushort4*)(w1b3 + base) = us;
    } else {
      size_t j = base - CW_W1;
      float4 v = *(const float4*)(w2l3 + j);
      ushort4 us = {nm_bf16r(v.x), nm_bf16r(v.y), nm_bf16r(v.z), nm_bf16r(v.w)};
      *(ushort4*)(w2b3 + j) = us;
    }
  } else if (bid < CWB + NTOK / 4) {
    int n = (bid - CWB) * 4 + (tid >> 6);
    int lane = tid & 63;
    int t = idx[n];
    float v0 = tok[(size_t)t * DD + lane]      + pos[(n % SEQ) * DD + lane];
    float v1 = tok[(size_t)t * DD + lane + 64] + pos[(n % SEQ) * DD + lane + 64];
    x[n * DD + lane]      = v0;
    x[n * DD + lane + 64] = v1;
    float s = v0 + v1;
#pragma unroll
    for (int o = 32; o > 0; o >>= 1) s += __shfl_xor(s, o, 64);
    float mu = s * (1.f / 128.f);
    float d0 = v0 - mu, d1 = v1 - mu;
    float q = d0 * d0 + d1 * d1;
#pragma unroll
    for (int o = 32; o > 0; o >>= 1) q += __shfl_xor(q, o, 64);
    float rstd = rsqrtf(q * (1.f / 128.f) + 1e-5f);
    xl[n * DD + lane]      = d0 * rstd * g[lane]      + b[lane];
    xl[n * DD + lane + 64] = d1 * rstd * g[lane + 64] + b[lane + 64];
  } else {
    if (tid < 72) zp[tid] = 0;                  // cnt[32] + offs[32] + tick[8]
  }
}

// x = tok_emb[idx] + pos_emb; LN1 (fallback path)
__global__ void nm_embed_ln(const int* __restrict__ idx, const float* __restrict__ tok,
                            const float* __restrict__ pos, const float* __restrict__ g,
                            const float* __restrict__ b, float* __restrict__ x,
                            float* __restrict__ xlf) {
  int n = blockIdx.x, lane = threadIdx.x;       // block = 64
  int t = idx[n];
  float v0 = tok[(size_t)t * DD + lane]      + pos[(n % SEQ) * DD + lane];
  float v1 = tok[(size_t)t * DD + lane + 64] + pos[(n % SEQ) * DD + lane + 64];
  x[n * DD + lane]      = v0;
  x[n * DD + lane + 64] = v1;
  float s = v0 + v1;
#pragma unroll
  for (int o = 32; o > 0; o >>= 1) s += __shfl_xor(s, o, 64);
  float mu = s * (1.f / 128.f);
  float d0 = v0 - mu, d1 = v1 - mu;
  float q = d0 * d0 + d1 * d1;
#pragma unroll
  for (int o = 32; o > 0; o >>= 1) q += __shfl_xor(q, o, 64);
  float rstd = rsqrtf(q * (1.f / 128.f) + 1e-5f);
  xlf[n * DD + lane]      = d0 * rstd * g[lane]      + b[lane];
  xlf[n * DD + lane + 64] = d1 * rstd * g[lane + 64] + b[lane + 64];
}

// LayerNorm (fallback path)
__global__ void nm_ln(const float* __restrict__ in, const float* __restrict__ g,
                      const float* __restrict__ b, float* __restrict__ out) {
  int n = blockIdx.x, lane = threadIdx.x;       // block = 64
  float v0 = in[n * DD + lane], v1 = in[n * DD + lane + 64];
  float s = v0 + v1;
#pragma unroll
  for (int o = 32; o > 0; o >>= 1) s += __shfl_xor(s, o, 64);
  float mu = s * (1.f / 128.f);
  float d0 = v0 - mu, d1 = v1 - mu;
  float q = d0 * d0 + d1 * d1;
#pragma unroll
  for (int o = 32; o > 0; o >>= 1) q += __shfl_xor(q, o, 64);
  float rstd = rsqrtf(q * (1.f / 128.f) + 1e-5f);
  out[n * DD + lane]      = d0 * rstd * g[lane]      + b[lane];
  out[n * DD + lane + 64] = d1 * rstd * g[lane + 64] + b[lane + 64];
}

// x += w0*yb[p0] + w1*yb[p1]; xl = LN(x); xb = bf16(xl) optional.
// block = 256 (4 waves, 1 token/wave); grid = NTOK/4
__global__ __launch_bounds__(256) void nm_combine_ln(
    const float* __restrict__ yb, const int* __restrict__ posm,
    const float* __restrict__ topw, float* __restrict__ x,
    const float* __restrict__ g, const float* __restrict__ b,
    float* __restrict__ xl, unsigned short* __restrict__ xb) {
  int n = blockIdx.x * 4 + (threadIdx.x >> 6);
  int lane = threadIdx.x & 63;
  float w0 = topw[2 * n], w1 = topw[2 * n + 1];
  int p0 = posm[2 * n], p1 = posm[2 * n + 1];
  float v0 = x[n * DD + lane]      + w0 * yb[(size_t)p0 * DD + lane]
                                   + w1 * yb[(size_t)p1 * DD + lane];
  float v1 = x[n * DD + lane + 64] + w0 * yb[(size_t)p0 * DD + lane + 64]
                                   + w1 * yb[(size_t)p1 * DD + lane + 64];
  x[n * DD + lane]      = v0;
  x[n * DD + lane + 64] = v1;
  float s = v0 + v1;
#pragma unroll
  for (int o = 32; o > 0; o >>= 1) s += __shfl_xor(s, o, 64);
  float mu = s * (1.f / 128.f);
  float d0 = v0 - mu, d1 = v1 - mu;
  float q = d0 * d0 + d1 * d1;
#pragma unroll
  for (int o = 32; o > 0; o >>= 1) q += __shfl_xor(q, o, 64);
  float rstd = rsqrtf(q * (1.f / 128.f) + 1e-5f);
  float o0 = d0 * rstd * g[lane]      + b[lane];
  float o1 = d1 * rstd * g[lane + 64] + b[lane + 64];
  xl[n * DD + lane]      = o0;
  xl[n * DD + lane + 64] = o1;
  if (xb) {
    xb[n * DD + lane]      = nm_bf16r(o0);
    xb[n * DD + lane + 64] = nm_bf16r(o1);
  }
}

// ===================== tiled f32 GEMM (MT x 64 tile) =====================
// Flags: 1=GATHER-A, 2=SILU, 4=BIAS, 16=GROUPED.  MT in {64,128}.
template<int F, int MT>
__global__ __launch_bounds__(256) void nm_gemm2(
    const float* __restrict__ A, const float* __restrict__ B,
    float* __restrict__ C, const float* __restrict__ bias,
    int M, int N, int K,
    const int* __restrict__ list, const int* __restrict__ cnt,
    const int* __restrict__ off) {
  constexpr bool GA = F & 1, SI = F & 2, BI = F & 4, GR = F & 16;
  constexpr int RG = MT / 64;
  __shared__ __align__(16) float As[64][MT + 4];
  __shared__ __align__(16) float Bs[64][68];
  int tid = threadIdx.x;
  int n0 = blockIdx.x * 64, m0 = blockIdx.y * MT;
  int Mloc = M, o = 0;
  const float* Bb = B;
  if constexpr (GR) {
    int e = blockIdx.z;
    Mloc = cnt[e];
    if (m0 >= Mloc) return;
    o = off[e];
    Bb = B + (size_t)e * (size_t)N * K;
  }
  int tm = tid & 15, tn = tid >> 4;
  float acc[RG * 4][4] = {};
  for (int kc = 0; kc < K; kc += 64) {
#pragma unroll
    for (int i = 0; i < RG * 4; ++i) {          // stage A: MT rows x 64 k
      int f = tid + 256 * i;
      int r = f >> 4, c4 = f & 15;
      int mi = m0 + r;
      if (mi >= Mloc) mi = m0;                  // clamp (grouped tail)
      const float* ar;
      if constexpr (GA) ar = A + (size_t)(list[o + mi] >> 1) * K;
      else              ar = A + (size_t)(o + mi) * K;
      float4 v = *(const float4*)(ar + kc + c4 * 4);
      int k = c4 * 4;
      As[k][r] = v.x; As[k + 1][r] = v.y; As[k + 2][r] = v.z; As[k + 3][r] = v.w;
    }
#pragma unroll
    for (int i = 0; i < 4; ++i) {               // stage B: 64 rows x 64 k
      int f = tid + 256 * i;
      int r = f >> 4, c4 = f & 15;
      const float* br = Bb + (size_t)(n0 + r) * K + kc + c4 * 4;
      float4 v = *(const float4*)br;
      int k = c4 * 4;
      Bs[k][r] = v.x; Bs[k + 1][r] = v.y; Bs[k + 2][r] = v.z; Bs[k + 3][r] = v.w;
    }
    __syncthreads();
#pragma unroll 16
    for (int k = 0; k < 64; ++k) {
      float4 b = *(const float4*)&Bs[k][tn * 4];
#pragma unroll
      for (int g2 = 0; g2 < RG; ++g2) {
        float4 a = *(const float4*)&As[k][g2 * 64 + tm * 4];
        acc[g2*4+0][0] = fmaf(a.x, b.x, acc[g2*4+0][0]);
        acc[g2*4+0][1] = fmaf(a.x, b.y, acc[g2*4+0][1]);
        acc[g2*4+0][2] = fmaf(a.x, b.z, acc[g2*4+0][2]);
        acc[g2*4+0][3] = fmaf(a.x, b.w, acc[g2*4+0][3]);
        acc[g2*4+1][0] = fmaf(a.y, b.x, acc[g2*4+1][0]);
        acc[g2*4+1][1] = fmaf(a.y, b.y, acc[g2*4+1][1]);
        acc[g2*4+1][2] = fmaf(a.y, b.z, acc[g2*4+1][2]);
        acc[g2*4+1][3] = fmaf(a.y, b.w, acc[g2*4+1][3]);
        acc[g2*4+2][0] = fmaf(a.z, b.x, acc[g2*4+2][0]);
        acc[g2*4+2][1] = fmaf(a.z, b.y, acc[g2*4+2][1]);
        acc[g2*4+2][2] = fmaf(a.z, b.z, acc[g2*4+2][2]);
        acc[g2*4+2][3] = fmaf(a.z, b.w, acc[g2*4+2][3]);
        acc[g2*4+3][0] = fmaf(a.w, b.x, acc[g2*4+3][0]);
        acc[g2*4+3][1] = fmaf(a.w, b.y, acc[g2*4+3][1]);
        acc[g2*4+3][2] = fmaf(a.w, b.z, acc[g2*4+3][2]);
        acc[g2*4+3][3] = fmaf(a.w, b.w, acc[g2*4+3][3]);
      }
    }
    __syncthreads();
  }
  float4 bv = {0.f, 0.f, 0.f, 0.f};
  if constexpr (BI) bv = *(const float4*)(bias + n0 + tn * 4);
#pragma unroll
  for (int g2 = 0; g2 < RG; ++g2) {
#pragma unroll
    for (int i = 0; i < 4; ++i) {
      int row = m0 + g2 * 64 + tm * 4 + i;
      if (GR && row >= Mloc) continue;
      float* cr = C + (size_t)(o + row) * N + n0 + tn * 4;
      float r0 = acc[g2 * 4 + i][0], r1 = acc[g2 * 4 + i][1];
      float r2 = acc[g2 * 4 + i][2], r3 = acc[g2 * 4 + i][3];
      if constexpr (BI) { r0 += bv.x; r1 += bv.y; r2 += bv.z; r3 += bv.w; }
      if constexpr (SI) { r0 = nm_silu(r0); r1 = nm_silu(r1); r2 = nm_silu(r2); r3 = nm_silu(r3); }
      float4 st = {r0, r1, r2, r3};
      *(float4*)cr = st;
    }
  }
}

// ===================== bf16 MFMA GEMM (layer-3 MoE only) =====================
template<int F, int KK>
__global__ __launch_bounds__(256) void nm_bgemm(
    const unsigned short* __restrict__ A, const unsigned short* __restrict__ B,
    float* __restrict__ Cf, unsigned short* __restrict__ Cb,
    const float* __restrict__ bias, int M, int N,
    const int* __restrict__ list, const int* __restrict__ cnt,
    const int* __restrict__ off) {
  constexpr bool GA = F & 1, SI = F & 2, BI = F & 4, SB = F & 8, GR = F & 16;
  int wave = threadIdx.x >> 6, lane = threadIdx.x & 63;
  int n0 = blockIdx.x * 32;
  int m0 = blockIdx.y * 128 + wave * 32;
  int Mloc = M, o = 0;
  const unsigned short* Bb = B;
  if constexpr (GR) {
    int e = blockIdx.z;
    Mloc = cnt[e];
    o = off[e];
    Bb = B + (size_t)e * (size_t)N * KK;
  }
  if (m0 >= Mloc) return;                       // per-wave exit (no barriers)
  int lr = lane & 15, lk = (lane >> 4) * 8;
  const unsigned short* arow[2];
#pragma unroll
  for (int i = 0; i < 2; ++i) {
    int mi = m0 + i * 16 + lr;
    if (mi >= Mloc) mi = Mloc - 1;              // clamp (dup row, masked on store)
    int r = GA ? (list[o + mi] >> 1) : (o + mi);
    arow[i] = A + (size_t)r * KK;
  }
  const unsigned short* brow[2] = { Bb + (size_t)(n0 + lr) * KK,
                                    Bb + (size_t)(n0 + 16 + lr) * KK };
  f32x4 acc[2][2] = {};
#pragma unroll
  for (int ks = 0; ks < KK / 32; ++ks) {
    int kb = ks * 32 + lk;
    short8v a0 = *(const short8v*)(arow[0] + kb);
    short8v a1 = *(const short8v*)(arow[1] + kb);
    short8v b0 = *(const short8v*)(brow[0] + kb);
    short8v b1 = *(const short8v*)(brow[1] + kb);
    acc[0][0] = __builtin_amdgcn_mfma_f32_16x16x32_bf16(a0, b0, acc[0][0], 0, 0, 0);
    acc[0][1] = __builtin_amdgcn_mfma_f32_16x16x32_bf16(a0, b1, acc[0][1], 0, 0, 0);
    acc[1][0] = __builtin_amdgcn_mfma_f32_16x16x32_bf16(a1, b0, acc[1][0], 0, 0, 0);
    acc[1][1] = __builtin_amdgcn_mfma_f32_16x16x32_bf16(a1, b1, acc[1][1], 0, 0, 0);
  }
  float bc[2] = {0.f, 0.f};
  if constexpr (BI) {
    bc[0] = bias[n0 + (lane & 15)];
    bc[1] = bias[n0 + 16 + (lane & 15)];
  }
#pragma unroll
  for (int i = 0; i < 2; ++i) {
    int rbase = m0 + i * 16 + (lane >> 4) * 4;
#pragma unroll
    for (int r = 0; r < 4; ++r) {
      int row = rbase + r;
      if (GR && row >= Mloc) continue;
#pragma unroll
      for (int j = 0; j < 2; ++j) {
        float v = acc[i][j][r];
        if constexpr (BI) v += bc[j];
        if constexpr (SI) v = nm_silu(v);
        int col = n0 + j * 16 + (lane & 15);
        if constexpr (SB) Cb[(size_t)(o + row) * N + col] = nm_bf16r(v);
        else              Cf[(size_t)(o + row) * N + col] = v;
      }
    }
  }
}

// ========== fused out-proj + residual + LN2 + gate + ROUTE (last block) ==========
__global__ __launch_bounds__(256) void nm_oplng(
    const float* __restrict__ ao, const float* __restrict__ w,
    const float* __restrict__ bias, float* __restrict__ x,
    const float* __restrict__ g, const float* __restrict__ b,
    float* __restrict__ xl, unsigned short* __restrict__ xlb,
    const float* __restrict__ gw,
    int* __restrict__ topi, float* __restrict__ topw, int* __restrict__ cnt,
    int* __restrict__ ticket, int* __restrict__ off, int* __restrict__ list,
    int* __restrict__ posm) {
  __shared__ __align__(16) float As[64][36];
  __shared__ __align__(16) float Bs[64][132];
  __shared__ float Ls[32][9];
  __shared__ int doR;
  __shared__ int cv[NEXP], lcur[NEXP];
  int tid = threadIdx.x;
  int m0 = blockIdx.x * 32;
  int tm = tid >> 5, tn = tid & 31;
  float acc[4][4] = {};
  for (int kc = 0; kc < DD; kc += 64) {
#pragma unroll
    for (int i = 0; i < 2; ++i) {
      int ch = tid + 256 * i, r = ch >> 4, c4 = ch & 15;
      float4 v = *(const float4*)(ao + (size_t)(m0 + r) * DD + kc + c4 * 4);
      int k = c4 * 4;
      As[k][r] = v.x; As[k + 1][r] = v.y; As[k + 2][r] = v.z; As[k + 3][r] = v.w;
    }
#pragma unroll
    for (int i = 0; i < 8; ++i) {
      int ch = tid + 256 * i, r = ch >> 4, c4 = ch & 15;
      float4 v = *(const float4*)(w + (size_t)r * DD + kc + c4 * 4);
      int k = c4 * 4;
      Bs[k][r] = v.x; Bs[k + 1][r] = v.y; Bs[k + 2][r] = v.z; Bs[k + 3][r] = v.w;
    }
    __syncthreads();
#pragma unroll 8
    for (int k = 0; k < 64; ++k) {
      float4 a = *(const float4*)&As[k][tm * 4];
      float4 bb = *(const float4*)&Bs[k][tn * 4];
      acc[0][0] = fmaf(a.x, bb.x, acc[0][0]); acc[0][1] = fmaf(a.x, bb.y, acc[0][1]);
      acc[0][2] = fmaf(a.x, bb.z, acc[0][2]); acc[0][3] = fmaf(a.x, bb.w, acc[0][3]);
      acc[1][0] = fmaf(a.y, bb.x, acc[1][0]); acc[1][1] = fmaf(a.y, bb.y, acc[1][1]);
      acc[1][2] = fmaf(a.y, bb.z, acc[1][2]); acc[1][3] = fmaf(a.y, bb.w, acc[1][3]);
      acc[2][0] = fmaf(a.z, bb.x, acc[2][0]); acc[2][1] = fmaf(a.z, bb.y, acc[2][1]);
      acc[2][2] = fmaf(a.z, bb.z, acc[2][2]); acc[2][3] = fmaf(a.z, bb.w, acc[2][3]);
      acc[3][0] = fmaf(a.w, bb.x, acc[3][0]); acc[3][1] = fmaf(a.w, bb.y, acc[3][1]);
      acc[3][2] = fmaf(a.w, bb.z, acc[3][2]); acc[3][3] = fmaf(a.w, bb.w, acc[3][3]);
    }
    __syncthreads();
  }
  float4 bv = *(const float4*)(bias + tn * 4);
  float rr[4][4], s1[4], s2[4];
#pragma unroll
  for (int i = 0; i < 4; ++i) {
    int rw = m0 + tm * 4 + i;
    float4 xv = *(const float4*)(x + (size_t)rw * DD + tn * 4);
    float r0 = acc[i][0] + bv.x + xv.x;
    float r1 = acc[i][1] + bv.y + xv.y;
    float r2 = acc[i][2] + bv.z + xv.z;
    float r3 = acc[i][3] + bv.w + xv.w;
    rr[i][0] = r0; rr[i][1] = r1; rr[i][2] = r2; rr[i][3] = r3;
    float4 st = {r0, r1, r2, r3};
    *(float4*)(x + (size_t)rw * DD + tn * 4) = st;
    s1[i] = r0 + r1 + r2 + r3;
    s2[i] = r0 * r0 + r1 * r1 + r2 * r2 + r3 * r3;
  }
#pragma unroll
  for (int o = 16; o >= 1; o >>= 1) {
#pragma unroll
    for (int i = 0; i < 4; ++i) {
      s1[i] += __shfl_xor(s1[i], o, 64);
      s2[i] += __shfl_xor(s2[i], o, 64);
    }
  }
  float4 gv  = *(const float4*)(g + tn * 4);
  float4 bbv = *(const float4*)(b + tn * 4);
#pragma unroll
  for (int i = 0; i < 4; ++i) {
    int rw = m0 + tm * 4 + i;
    float mu = s1[i] * (1.f / 128.f);
    float var = s2[i] * (1.f / 128.f) - mu * mu;
    float rstd = rsqrtf(var + 1e-5f);
    float y0 = (rr[i][0] - mu) * rstd * gv.x + bbv.x;
    float y1 = (rr[i][1] - mu) * rstd * gv.y + bbv.y;
    float y2 = (rr[i][2] - mu) * rstd * gv.z + bbv.z;
    float y3 = (rr[i][3] - mu) * rstd * gv.w + bbv.w;
    float4 yv = {y0, y1, y2, y3};
    *(float4*)(xl + (size_t)rw * DD + tn * 4) = yv;
    if (xlb) {
      ushort4 us = {nm_bf16r(y0), nm_bf16r(y1), nm_bf16r(y2), nm_bf16r(y3)};
      *(ushort4*)(xlb + (size_t)rw * DD + tn * 4) = us;
    }
    *(float4*)&Bs[tm * 4 + i][tn * 4] = yv;     // stash for gate (f32)
  }
  __syncthreads();
  // gate: thread = (row, expert)
  int grow = tid >> 3, ge = tid & 7;
  const float4* xr = (const float4*)&Bs[grow][0];
  const float4* wr = (const float4*)(gw + (size_t)ge * DD);
  float sx = 0.f, sy = 0.f, sz = 0.f, sw = 0.f;
#pragma unroll
  for (int k2 = 0; k2 < 32; ++k2) {
    float4 a = xr[k2], w4 = wr[k2];
    sx = fmaf(a.x, w4.x, sx); sy = fmaf(a.y, w4.y, sy);
    sz = fmaf(a.z, w4.z, sz); sw = fmaf(a.w, w4.w, sw);
  }
  Ls[grow][ge] = (sx + sy) + (sz + sw);
  __syncthreads();
  if (ge == 0) {
    float gl[NEXP];
#pragma unroll
    for (int e = 0; e < NEXP; ++e) gl[e] = Ls[grow][e];
    int i0 = 0;
#pragma unroll
    for (int e = 1; e < NEXP; ++e) if (gl[e] > gl[i0]) i0 = e;
    int i1 = (i0 == 0) ? 1 : 0;
#pragma unroll
    for (int e = 0; e < NEXP; ++e) { if (e != i0 && gl[e] > gl[i1]) i1 = e; }
    float p1 = __expf(gl[i1] - gl[i0]);         // renormalized top-2 softmax
    float inv = 1.f / (1.f + p1);
    int n = m0 + grow;
    topi[2 * n] = i0; topi[2 * n + 1] = i1;
    topw[2 * n] = inv; topw[2 * n + 1] = p1 * inv;
    atomicAdd(cnt + i0, 1);
    atomicAdd(cnt + i1, 1);
  }
  // ---- fused routing: last-arriving block does prefix + scatter ----
  __syncthreads();
  if (tid == 0) {
    __threadfence();
    doR = (atomicAdd(ticket, 1) == 63);
    if (doR) __threadfence();
  }
  __syncthreads();
  if (doR) {
    if (tid < NEXP) cv[tid] = atomicAdd(cnt + tid, 0);
    __syncthreads();
    if (tid < NEXP) {
      int o2 = 0;
      for (int e = 0; e < tid; ++e) o2 += cv[e];
      lcur[tid] = o2;
      off[tid] = o2;
    }
    __syncthreads();
    for (int t = tid; t < 2 * NTOK; t += 256) {
      int e = topi[t];
      int p = atomicAdd(&lcur[e], 1);
      list[p] = t;
      posm[t] = p;
    }
  }
}

// ===================== attention v3: 512 blocks, swizzled K/V =====================
__global__ __launch_bounds__(256) void nm_attn3(const float* __restrict__ qkv,
                                                float* __restrict__ o) {
  __shared__ __align__(16) float smem[2 * SEQ * DHEAD];   // 64 KB
  float4* K4 = (float4*)smem;                   // [SEQ][8] swizzled chunks
  float4* V4 = (float4*)(smem + SEQ * DHEAD);
  int bh = blockIdx.x;
  int b = bh >> 2, h = bh & 3;
  int qt = blockIdx.y;
  int tid = threadIdx.x;
  const float* base = qkv + (size_t)b * SEQ * 384;
  for (int f = tid; f < SEQ * 8; f += 256) {
    int t = f >> 3, c4 = f & 7;
    int pc = (c4 + (t >> 4)) & 7;
    K4[t * 8 + pc] = *(const float4*)(base + (size_t)t * 384 + 128 + h * DHEAD + c4 * 4);
    V4[t * 8 + pc] = *(const float4*)(base + (size_t)t * 384 + 256 + h * DHEAD + c4 * 4);
  }
  __syncthreads();
  int qi = tid >> 4, slot = tid & 15;
  int tq = qt * 16 + qi;
  float qv[DHEAD];
  const float4* q4 = (const float4*)(base + (size_t)tq * 384 + h * DHEAD);
#pragma unroll
  for (int k = 0; k < 8; ++k) {
    float4 v = q4[k];
    qv[4*k] = v.x; qv[4*k+1] = v.y; qv[4*k+2] = v.z; qv[4*k+3] = v.w;
  }
  float m = -1e30f, s = 0.f, acc[DHEAD];
#pragma unroll
  for (int d = 0; d < DHEAD; ++d) acc[d] = 0.f;
  const float scale = 0.17677669529663687f;     // 1/sqrt(32)
  int sw = slot & 7;
  for (int jj = 0; jj < 16; ++jj) {
    int j = slot * 16 + jj;
    float sc = 0.f;
#pragma unroll
    for (int k = 0; k < 8; ++k) {
      float4 v = K4[j * 8 + ((k + sw) & 7)];
      sc += qv[4*k]*v.x + qv[4*k+1]*v.y + qv[4*k+2]*v.z + qv[4*k+3]*v.w;
    }
    sc *= scale;
    float mn = fmaxf(m, sc);
    float f = __expf(m - mn), p = __expf(sc - mn);
    s = s * f + p;
#pragma unroll
    for (int k = 0; k < 8; ++k) {
      float4 v = V4[j * 8 + ((k + sw) & 7)];
      acc[4*k]   = acc[4*k]  * f + p * v.x;
      acc[4*k+1] = acc[4*k+1]* f + p * v.y;
      acc[4*k+2] = acc[4*k+2]* f + p * v.z;
      acc[4*k+3] = acc[4*k+3]* f + p * v.w;
    }
    m = mn;
  }
  __syncthreads();                              // K/V consumed -> reuse as cbuf
  float* cb = smem;                             // [256][34]: 32 acc + m + s
  float* my = cb + (qi * 16 + slot) * 34;
#pragma unroll
  for (int d = 0; d < DHEAD; ++d) my[d] = acc[d];
  my[32] = m;
  my[33] = s;
  __syncthreads();
  int q2 = tid >> 4, dg = tid & 15;
  const float* qb = cb + q2 * 16 * 34;
  float M = qb[32];
#pragma unroll
  for (int t = 1; t < 16; ++t) M = fmaxf(M, qb[t * 34 + 32]);
  float S = 0.f, v0 = 0.f, v1 = 0.f;
#pragma unroll
  for (int t = 0; t < 16; ++t) {
    float w = __expf(qb[t * 34 + 32] - M);
    S += qb[t * 34 + 33] * w;
    v0 += w * qb[t * 34 + dg * 2];
    v1 += w * qb[t * 34 + dg * 2 + 1];
  }
  float inv = 1.f / S;
  float* orow = o + (size_t)(b * SEQ + qt * 16 + q2) * DD + h * DHEAD + dg * 2;
  orow[0] = v0 * inv;
  orow[1] = v1 * inv;
}

// ===================== fallback-only kernels =====================
__global__ void nm_qkv(const float* __restrict__ xl, const float* __restrict__ w,
                       const float* __restrict__ bias, float* __restrict__ qkv) {
  __shared__ __align__(16) float xs[DD];
  int n = blockIdx.x, tid = threadIdx.x;        // block = 128
  xs[tid] = xl[n * DD + tid];
  __syncthreads();
#pragma unroll
  for (int jj = 0; jj < 3; ++jj) {
    int j = tid + jj * 128;
    qkv[(size_t)n * 384 + j] = nm_dotv<32>(xs, w + (size_t)j * DD) + bias[j];
  }
}

__global__ void nm_outproj(const float* __restrict__ ao, const float* __restrict__ w,
                           const float* __restrict__ bias, float* __restrict__ x) {
  __shared__ __align__(16) float os[DD];
  int n = blockIdx.x, tid = threadIdx.x;        // block = 128
  os[tid] = ao[n * DD + tid];
  __syncthreads();
  x[n * DD + tid] += nm_dotv<32>(os, w + (size_t)tid * DD) + bias[tid];
}

__global__ void nm_moe(const float* __restrict__ x2, const float* __restrict__ gw,
                       const float* __restrict__ w1, const float* __restrict__ w2,
                       float* __restrict__ x) {
  __shared__ __align__(16) float xs[DD];
  __shared__ __align__(16) float hs[DHID];
  __shared__ float gl[NEXP];
  __shared__ int   ei[2];
  __shared__ float ew[2];
  int n = blockIdx.x, tid = threadIdx.x;        // block = 256
  if (tid < DD) xs[tid] = x2[n * DD + tid];
  __syncthreads();
  if (tid < NEXP) gl[tid] = nm_dotv<32>(xs, gw + (size_t)tid * DD);
  __syncthreads();
  if (tid == 0) {
    int i0 = 0;
#pragma unroll
    for (int e = 1; e < NEXP; ++e) if (gl[e] > gl[i0]) i0 = e;
    int i1 = (i0 == 0) ? 1 : 0;
    for (int e = 0; e < NEXP; ++e) { if (e == i0) continue; if (gl[e] > gl[i1]) i1 = e; }
    float p1 = __expf(gl[i1] - gl[i0]);
    float inv = 1.f / (1.f + p1);
    ei[0] = i0; ei[1] = i1; ew[0] = inv; ew[1] = p1 * inv;
  }
  __syncthreads();
  float yacc = 0.f;
  for (int t2 = 0; t2 < 2; ++t2) {
    int e = ei[t2];
    float wt = ew[t2];
    const float* w1e = w1 + (size_t)e * DHID * DD;
#pragma unroll
    for (int jj = 0; jj < 2; ++jj) {
      int j = tid + jj * 256;
      float a = nm_dotv<32>(xs, w1e + (size_t)j * DD);
      hs[j] = nm_silu(a);
    }
    __syncthreads();
    if (tid < DD) yacc += wt * nm_dotv<128>(hs, w2 + ((size_t)e * DD + tid) * DHID);
    __syncthreads();
  }
  if (tid < DD) x[n * DD + tid] += yacc;
}

__global__ __launch_bounds__(256) void nm_lmhead_f32(
    const float* __restrict__ xf, const float* __restrict__ lmw,
    float* __restrict__ out) {
  int wave = threadIdx.x >> 6, lane = threadIdx.x & 63;
  int wr = wave >> 1, wc = wave & 1;
  int row0 = blockIdx.y * 128 + wr * 64;
  int col0 = blockIdx.x * 128 + wc * 64;
  int lr = lane & 15, lk = (lane >> 4) * 8;
  f32x4 acc[4][4] = {};
#pragma unroll
  for (int ks = 0; ks < 4; ++ks) {
    int kb = ks * 32 + lk;
    short8v a[4], b[4];
#pragma unroll
    for (int i = 0; i < 4; ++i)
      a[i] = nm_cvt8(xf + (size_t)(row0 + i * 16 + lr) * DD + kb);
#pragma unroll
    for (int j = 0; j < 4; ++j) {
      int c = col0 + j * 16 + lr;
      if (c < NVOCAB) b[j] = nm_cvt8(lmw + (size_t)c * DD + kb);
      else {
        short8v z;
#pragma unroll
        for (int e = 0; e < 8; ++e) z[e] = 0;
        b[j] = z;
      }
    }
#pragma unroll
    for (int i = 0; i < 4; ++i)
#pragma unroll
      for (int j = 0; j < 4; ++j)
        acc[i][j] = __builtin_amdgcn_mfma_f32_16x16x32_bf16(a[i], b[j], acc[i][j], 0, 0, 0);
  }
  int cr = (lane >> 4) * 4;
#pragma unroll
  for (int j = 0; j < 4; ++j) {
    int c = col0 + j * 16 + (lane & 15);
    if (c < NVOCAB) {
#pragma unroll
      for (int i = 0; i < 4; ++i)
#pragma unroll
        for (int r = 0; r < 4; ++r)
          out[(size_t)(row0 + i * 16 + cr + r) * NVOCAB + c] = acc[i][j][r];
    }
  }
}

// ===== LM head (LDS-staged, coalesced epilogue; converts lm_w f32->bf16 in
// staging). grid (rows=16, cols=393): consecutive blocks share the B col-tile.
__global__ __launch_bounds__(256) void nm_lmhead2(
    const unsigned short* __restrict__ xfb, const float* __restrict__ lmw,
    float* __restrict__ out) {
  __shared__ __align__(16) unsigned char smem[132 * 128 * 4];  // 67.5 KB
  unsigned short* Ab = (unsigned short*)smem;
  unsigned short* Bb = Ab + 128 * 128;
  int tid = threadIdx.x;
  int row0 = blockIdx.x * 128, col0 = blockIdx.y * 128;
#pragma unroll
  for (int i = 0; i < 8; ++i) {
    int ch = tid + i * 256;
    int r = ch >> 4, s = ch & 15;
    int sg = s ^ (r & 7);                       // swizzled source slot
    *(short8v*)&Ab[r * 128 + s * 8] =
        *(const short8v*)(xfb + (size_t)(row0 + r) * DD + sg * 8);
    short8v bv;
    int browg = col0 + r;
    if (browg < NVOCAB) {
      bv = nm_cvt8(lmw + (size_t)browg * DD + sg * 8);
    } else {
#pragma unroll
      for (int e = 0; e < 8; ++e) bv[e] = 0;
    }
    *(short8v*)&Bb[r * 128 + s * 8] = bv;
  }
  __syncthreads();
  int wave = tid >> 6, lane = tid & 63;
  int wr = wave >> 1, wc = wave & 1;
  int lr = lane & 15, hk = lane >> 4;
  f32x4 acc[4][4] = {};
#pragma unroll
  for (int ks = 0; ks < 4; ++ks) {
    int sg = ks * 4 + hk;
    int sx = (sg ^ (lr & 7)) * 8;
    short8v a[4], b[4];
#pragma unroll
    for (int i = 0; i < 4; ++i)
      a[i] = *(const short8v*)&Ab[(wr * 64 + i * 16 + lr) * 128 + sx];
#pragma unroll
    for (int j = 0; j < 4; ++j)
      b[j] = *(const short8v*)&Bb[(wc * 64 + j * 16 + lr) * 128 + sx];
#pragma unroll
    for (int i = 0; i < 4; ++i)
#pragma unroll
      for (int j = 0; j < 4; ++j)
        acc[i][j] = __builtin_amdgcn_mfma_f32_16x16x32_bf16(a[i], b[j], acc[i][j], 0, 0, 0);
  }
  __syncthreads();
  float* Cs = (float*)smem;
  int hi4 = hk * 4;
#pragma unroll
  for (int j = 0; j < 4; ++j)
#pragma unroll
    for (int i = 0; i < 4; ++i)
#pragma unroll
      for (int r = 0; r < 4; ++r)
        Cs[(wr * 64 + i * 16 + hi4 + r) * 132 + wc * 64 + j * 16 + lr] = acc[i][j][r];
  __syncthreads();
  bool full = (col0 + 128 <= NVOCAB);
#pragma unroll 4
  for (int rr = 0; rr < 32; ++rr) {
    int row = wave * 32 + rr;
    float v0 = Cs[row * 132 + lane];
    float v1 = Cs[row * 132 + 64 + lane];
    size_t base = (size_t)(row0 + row) * NVOCAB + col0;
    if (full) {
      out[base + lane] = v0;
      out[base + 64 + lane] = v1;
    } else {
      if (col0 + lane < NVOCAB)      out[base + lane] = v0;
      if (col0 + 64 + lane < NVOCAB) out[base + 64 + lane] = v1;
    }
  }
}

extern "C" void kernel_launch(void* const* d_in, const int* in_sizes, int n_in,
                              void* d_out, int out_size, void* d_ws, size_t ws_size,
                              hipStream_t stream) {
  const int*   idx   = (const int*)  d_in[0];
  const float* tok   = (const float*)d_in[1];
  const float* pos   = (const float*)d_in[2];
  const float* ln1g  = (const float*)d_in[3];
  const float* ln1b  = (const float*)d_in[4];
  const float* inw   = (const float*)d_in[5];
  const float* inb   = (const float*)d_in[6];
  const float* outw  = (const float*)d_in[7];
  const float* outb  = (const float*)d_in[8];
  const float* ln2g  = (const float*)d_in[9];
  const float* ln2b  = (const float*)d_in[10];
  const float* gatew = (const float*)d_in[11];
  const float* w1    = (const float*)d_in[12];
  const float* w2    = (const float*)d_in[13];
  const float* lnfg  = (const float*)d_in[14];
  const float* lnfb  = (const float*)d_in[15];
  const float* lmw   = (const float*)d_in[16];
  float* out = (float*)d_out;

  float* ws   = (float*)d_ws;
  float* x    = ws;                              // 262144 f32
  float* xl   = x    + NTOK * DD;                // 262144
  float* qkv  = xl   + NTOK * DD;                // 786432
  float* ao   = qkv  + NTOK * 384;               // 262144
  float* topw = ao   + NTOK * DD;                // 4096
  float* H    = topw + 2 * NTOK;                 // 2097152 (f32, layers 0-2)
  float* yb   = H    + 2 * NTOK * DHID;          // 524288
  int*   topi = (int*)(yb + 2 * NTOK * DD);      // 4096
  int*   list = topi + 2 * NTOK;
  int*   posm = list + 2 * NTOK;
  int*   cnt  = posm + 2 * NTOK;                 // 32
  int*   offs = cnt  + NLAYER * NEXP;            // 32
  int*   tick = offs + NLAYER * NEXP;            // 8
  unsigned short* xlb  = (unsigned short*)(tick + 8);      // 262144
  unsigned short* Hb   = xlb + NTOK * DD;        // 2097152 (bf16, layer 3)
  unsigned short* xfb  = Hb  + 2 * NTOK * DHID;  // 262144
  unsigned short* w1b3 = xfb + NTOK * DD;        // 524288
  unsigned short* w2b3 = w1b3 + NEXP * DHID * DD;  // 524288
  const size_t need = (size_t)((char*)(w2b3 + NEXP * DD * DHID) - (char*)d_ws);
  const bool pre = (ws_size >= need);

  const float* w1l3 = w1 + (size_t)3 * NEXP * DHID * DD;
  const float* w2l3 = w2 + (size_t)3 * NEXP * DD * DHID;

  if (pre) {
    nm_init<<<CWB + NTOK / 4 + 1, 256, 0, stream>>>(
        idx, tok, pos, ln1g, ln1b, w1l3, w2l3, x, xl, w1b3, w2b3, cnt);
    for (int l = 0; l < NLAYER; ++l) {
      // QKV (f32): [2048,384] = xl @ in_w^T + b   (MT=64 -> 192 blocks)
      nm_gemm2<4, 64><<<dim3(384 / 64, NTOK / 64), 256, 0, stream>>>(
          xl, inw + (size_t)l * 384 * DD, qkv, inb + (size_t)l * 384,
          NTOK, 384, DD, nullptr, nullptr, nullptr);
      nm_attn3<<<dim3(NBATCH * NHEAD, SEQ / 16), 256, 0, stream>>>(qkv, ao);
      // fused out-proj + residual + LN2 + gate + route (last block)
      nm_oplng<<<NTOK / 32, 256, 0, stream>>>(
          ao, outw + (size_t)l * DD * DD, outb + (size_t)l * DD, x,
          ln2g + l * DD, ln2b + l * DD, xl, (l == 3) ? xlb : (unsigned short*)nullptr,
          gatew + (size_t)l * NEXP * DD, topi, topw, cnt + l * NEXP,
          tick + l, offs + l * NEXP, list, posm);
      int* cnt_l = cnt + l * NEXP;
      int* off_l = offs + l * NEXP;
      if (l < 3) {
        // f32 grouped expert GEMMs (routing-safe), MT=64 for parallelism
        const float* w1l = w1 + (size_t)l * NEXP * DHID * DD;
        const float* w2l = w2 + (size_t)l * NEXP * DD * DHID;
        nm_gemm2<19, 64><<<dim3(DHID / 64, 2 * NTOK / 64, NEXP), 256, 0, stream>>>(
            xl, w1l, H, nullptr, 0, DHID, DD, list, cnt_l, off_l);
        nm_gemm2<16, 64><<<dim3(DD / 64, 2 * NTOK / 64, NEXP), 256, 0, stream>>>(
            H, w2l, yb, nullptr, 0, DD, DHID, nullptr, cnt_l, off_l);
      } else {
        // layer-3 MoE: bf16 MFMA (no routing downstream -> safe)
        nm_bgemm<27, 128><<<dim3(DHID / 32, 32, NEXP), 256, 0, stream>>>(
            xlb, w1b3, nullptr, Hb, nullptr, 0, DHID, list, cnt_l, off_l);
        nm_bgemm<16, 512><<<dim3(DD / 32, 32, NEXP), 256, 0, stream>>>(
            Hb, w2b3, yb, nullptr, nullptr, 0, DD, nullptr, cnt_l, off_l);
      }
      const float* gN = (l < NLAYER - 1) ? ln1g + (l + 1) * DD : lnfg;
      const float* bN = (l < NLAYER - 1) ? ln1b + (l + 1) * DD : lnfb;
      nm_combine_ln<<<NTOK / 4, 256, 0, stream>>>(
          yb, posm, topw, x, gN, bN, xl,
          (l == NLAYER - 1) ? xfb : (unsigned short*)nullptr);
    }
    nm_lmhead2<<<dim3(NTOK / 128, VPAD / 128), 256, 0, stream>>>(xfb, lmw, out);
  } else {
    // compact fallback: per-token f32 path
    nm_embed_ln<<<NTOK, 64, 0, stream>>>(idx, tok, pos, ln1g, ln1b, x, xl);
    for (int l = 0; l < NLAYER; ++l) {
      nm_qkv<<<NTOK, 128, 0, stream>>>(xl, inw + (size_t)l * 384 * DD,
                                       inb + (size_t)l * 384, qkv);
      nm_attn3<<<dim3(NBATCH * NHEAD, SEQ / 16), 256, 0, stream>>>(qkv, ao);
      nm_outproj<<<NTOK, 128, 0, stream>>>(ao, outw + (size_t)l * DD * DD,
                                           outb + (size_t)l * DD, x);
      nm_ln<<<NTOK, 64, 0, stream>>>(x, ln2g + l * DD, ln2b + l * DD, xl);
      nm_moe<<<NTOK, 256, 0, stream>>>(xl, gatew + (size_t)l * NEXP * DD,
                                       w1 + (size_t)l * NEXP * DHID * DD,
                                       w2 + (size_t)l * NEXP * DD * DHID, x);
      const float* gN = (l < NLAYER - 1) ? ln1g + (l + 1) * DD : lnfg;
      const float* bN = (l < NLAYER - 1) ? ln1b + (l + 1) * DD : lnfb;
      nm_ln<<<NTOK, 64, 0, stream>>>(x, gN, bN, xl);
    }
    nm_lmhead_f32<<<dim3(VPAD / 128, NTOK / 128), 256, 0, stream>>>(xl, lmw, out);
  }
}

// Round 15
// 752.881 us; speedup vs baseline: 1.1093x; 1.1093x over previous
//
#include <hip/hip_runtime.h>
#include <math.h>

// ---- problem constants ----
#define NTOK 2048      // B*T
#define DD   128       // model dim D
#define NHEAD 4
#define DHEAD 32
#define NLAYER 4
#define NEXP 8
#define DHID 512
#define NVOCAB 50257
#define VPAD  50304    // 393*128
#define SEQ   256
#define NBATCH 8

typedef __attribute__((ext_vector_type(8))) short short8v;   // 8 bf16 in 4 VGPRs
typedef __attribute__((ext_vector_type(4))) float f32x4;

__device__ __forceinline__ unsigned short nm_bf16r(float f) {
  unsigned u = __float_as_uint(f);
  u += 0x7fffu + ((u >> 16) & 1u);          // RNE
  return (unsigned short)(u >> 16);
}

__device__ __forceinline__ float nm_silu(float a) {
  return a / (1.f + __expf(-a));
}

template<int N4>
__device__ __forceinline__ float nm_dotv(const float* __restrict__ a,
                                         const float* __restrict__ w) {
  const float4* a4 = (const float4*)a;
  const float4* w4 = (const float4*)w;
  float sx = 0.f, sy = 0.f, sz = 0.f, sw = 0.f;
#pragma unroll 16
  for (int k = 0; k < N4; ++k) {
    float4 av = a4[k], wv = w4[k];
    sx = fmaf(av.x, wv.x, sx);
    sy = fmaf(av.y, wv.y, sy);
    sz = fmaf(av.z, wv.z, sz);
    sw = fmaf(av.w, wv.w, sw);
  }
  return (sx + sy) + (sz + sw);
}

// ===================== fused init: weight cvt + embed+LN1 + counter zero =====================
#define C3_LMW 6438912ull                       // VPAD*DD
#define C3_W1  6963200ull                       // + 8*512*128
#define C3_ALL 7487488ull                       // + 8*128*512
#define CVTB   7312                             // C3_ALL / 1024
__global__ __launch_bounds__(256) void nm_init(
    const int* __restrict__ idx, const float* __restrict__ tok,
    const float* __restrict__ pos, const float* __restrict__ g,
    const float* __restrict__ b, const float* __restrict__ lmw,
    const float* __restrict__ w1l3, const float* __restrict__ w2l3,
    float* __restrict__ x, float* __restrict__ xl,
    unsigned short* __restrict__ lmwb, unsigned short* __restrict__ w1b3,
    unsigned short* __restrict__ w2b3, int* __restrict__ zp) {
  int bid = blockIdx.x, tid = threadIdx.x;
  if (bid < CVTB) {
    size_t base = ((size_t)bid * 256 + tid) * 4;
    if (base < (size_t)NVOCAB * DD) {
      float4 v = *(const float4*)(lmw + base);
      ushort4 us = {nm_bf16r(v.x), nm_bf16r(v.y), nm_bf16r(v.z), nm_bf16r(v.w)};
      *(ushort4*)(lmwb + base) = us;
    } else if (base < C3_LMW) {
      ushort4 us = {0, 0, 0, 0};
      *(ushort4*)(lmwb + base) = us;
    } else if (base < C3_W1) {
      size_t j = base - C3_LMW;
      float4 v = *(const float4*)(w1l3 + j);
      ushort4 us = {nm_bf16r(v.x), nm_bf16r(v.y), nm_bf16r(v.z), nm_bf16r(v.w)};
      *(ushort4*)(w1b3 + j) = us;
    } else {
      size_t j = base - C3_W1;
      float4 v = *(const float4*)(w2l3 + j);
      ushort4 us = {nm_bf16r(v.x), nm_bf16r(v.y), nm_bf16r(v.z), nm_bf16r(v.w)};
      *(ushort4*)(w2b3 + j) = us;
    }
  } else if (bid < CVTB + NTOK / 4) {
    int n = (bid - CVTB) * 4 + (tid >> 6);
    int lane = tid & 63;
    int t = idx[n];
    float v0 = tok[(size_t)t * DD + lane]      + pos[(n % SEQ) * DD + lane];
    float v1 = tok[(size_t)t * DD + lane + 64] + pos[(n % SEQ) * DD + lane + 64];
    x[n * DD + lane]      = v0;
    x[n * DD + lane + 64] = v1;
    float s = v0 + v1;
#pragma unroll
    for (int o = 32; o > 0; o >>= 1) s += __shfl_xor(s, o, 64);
    float mu = s * (1.f / 128.f);
    float d0 = v0 - mu, d1 = v1 - mu;
    float q = d0 * d0 + d1 * d1;
#pragma unroll
    for (int o = 32; o > 0; o >>= 1) q += __shfl_xor(q, o, 64);
    float rstd = rsqrtf(q * (1.f / 128.f) + 1e-5f);
    xl[n * DD + lane]      = d0 * rstd * g[lane]      + b[lane];
    xl[n * DD + lane + 64] = d1 * rstd * g[lane + 64] + b[lane + 64];
  } else {
    if (tid < 72) zp[tid] = 0;                  // cnt[32] + offs[32] + tick[8]
  }
}

// x = tok_emb[idx] + pos_emb; LN1 (fallback path)
__global__ void nm_embed_ln(const int* __restrict__ idx, const float* __restrict__ tok,
                            const float* __restrict__ pos, const float* __restrict__ g,
                            const float* __restrict__ b, float* __restrict__ x,
                            float* __restrict__ xlf) {
  int n = blockIdx.x, lane = threadIdx.x;       // block = 64
  int t = idx[n];
  float v0 = tok[(size_t)t * DD + lane]      + pos[(n % SEQ) * DD + lane];
  float v1 = tok[(size_t)t * DD + lane + 64] + pos[(n % SEQ) * DD + lane + 64];
  x[n * DD + lane]      = v0;
  x[n * DD + lane + 64] = v1;
  float s = v0 + v1;
#pragma unroll
  for (int o = 32; o > 0; o >>= 1) s += __shfl_xor(s, o, 64);
  float mu = s * (1.f / 128.f);
  float d0 = v0 - mu, d1 = v1 - mu;
  float q = d0 * d0 + d1 * d1;
#pragma unroll
  for (int o = 32; o > 0; o >>= 1) q += __shfl_xor(q, o, 64);
  float rstd = rsqrtf(q * (1.f / 128.f) + 1e-5f);
  xlf[n * DD + lane]      = d0 * rstd * g[lane]      + b[lane];
  xlf[n * DD + lane + 64] = d1 * rstd * g[lane + 64] + b[lane + 64];
}

// LayerNorm (fallback path)
__global__ void nm_ln(const float* __restrict__ in, const float* __restrict__ g,
                      const float* __restrict__ b, float* __restrict__ out) {
  int n = blockIdx.x, lane = threadIdx.x;       // block = 64
  float v0 = in[n * DD + lane], v1 = in[n * DD + lane + 64];
  float s = v0 + v1;
#pragma unroll
  for (int o = 32; o > 0; o >>= 1) s += __shfl_xor(s, o, 64);
  float mu = s * (1.f / 128.f);
  float d0 = v0 - mu, d1 = v1 - mu;
  float q = d0 * d0 + d1 * d1;
#pragma unroll
  for (int o = 32; o > 0; o >>= 1) q += __shfl_xor(q, o, 64);
  float rstd = rsqrtf(q * (1.f / 128.f) + 1e-5f);
  out[n * DD + lane]      = d0 * rstd * g[lane]      + b[lane];
  out[n * DD + lane + 64] = d1 * rstd * g[lane + 64] + b[lane + 64];
}

// x += w0*yb[p0] + w1*yb[p1]; xl = LN(x) (f32 always); xb = bf16(xl) optional
__global__ void nm_combine_ln(const float* __restrict__ yb, const int* __restrict__ posm,
                              const float* __restrict__ topw, float* __restrict__ x,
                              const float* __restrict__ g, const float* __restrict__ b,
                              float* __restrict__ xl, unsigned short* __restrict__ xb) {
  int n = blockIdx.x, lane = threadIdx.x;
  float w0 = topw[2 * n], w1 = topw[2 * n + 1];
  int p0 = posm[2 * n], p1 = posm[2 * n + 1];
  float v0 = x[n * DD + lane]      + w0 * yb[(size_t)p0 * DD + lane]
                                   + w1 * yb[(size_t)p1 * DD + lane];
  float v1 = x[n * DD + lane + 64] + w0 * yb[(size_t)p0 * DD + lane + 64]
                                   + w1 * yb[(size_t)p1 * DD + lane + 64];
  x[n * DD + lane]      = v0;
  x[n * DD + lane + 64] = v1;
  float s = v0 + v1;
#pragma unroll
  for (int o = 32; o > 0; o >>= 1) s += __shfl_xor(s, o, 64);
  float mu = s * (1.f / 128.f);
  float d0 = v0 - mu, d1 = v1 - mu;
  float q = d0 * d0 + d1 * d1;
#pragma unroll
  for (int o = 32; o > 0; o >>= 1) q += __shfl_xor(q, o, 64);
  float rstd = rsqrtf(q * (1.f / 128.f) + 1e-5f);
  float o0 = d0 * rstd * g[lane]      + b[lane];
  float o1 = d1 * rstd * g[lane + 64] + b[lane + 64];
  xl[n * DD + lane]      = o0;
  xl[n * DD + lane + 64] = o1;
  if (xb) {
    xb[n * DD + lane]      = nm_bf16r(o0);
    xb[n * DD + lane + 64] = nm_bf16r(o1);
  }
}

// ===================== tiled f32 GEMM (MT x 64 tile) =====================
// Flags: 1=GATHER-A, 2=SILU, 4=BIAS, 16=GROUPED.  MT in {64,128}.
template<int F, int MT>
__global__ __launch_bounds__(256) void nm_gemm2(
    const float* __restrict__ A, const float* __restrict__ B,
    float* __restrict__ C, const float* __restrict__ bias,
    int M, int N, int K,
    const int* __restrict__ list, const int* __restrict__ cnt,
    const int* __restrict__ off) {
  constexpr bool GA = F & 1, SI = F & 2, BI = F & 4, GR = F & 16;
  constexpr int RG = MT / 64;
  __shared__ __align__(16) float As[64][MT + 4];
  __shared__ __align__(16) float Bs[64][68];
  int tid = threadIdx.x;
  int n0 = blockIdx.x * 64, m0 = blockIdx.y * MT;
  int Mloc = M, o = 0;
  const float* Bb = B;
  if constexpr (GR) {
    int e = blockIdx.z;
    Mloc = cnt[e];
    if (m0 >= Mloc) return;
    o = off[e];
    Bb = B + (size_t)e * (size_t)N * K;
  }
  int tm = tid & 15, tn = tid >> 4;
  float acc[RG * 4][4] = {};
  for (int kc = 0; kc < K; kc += 64) {
#pragma unroll
    for (int i = 0; i < RG * 4; ++i) {          // stage A: MT rows x 64 k
      int f = tid + 256 * i;
      int r = f >> 4, c4 = f & 15;
      int mi = m0 + r;
      if (mi >= Mloc) mi = m0;                  // clamp (grouped tail)
      const float* ar;
      if constexpr (GA) ar = A + (size_t)(list[o + mi] >> 1) * K;
      else              ar = A + (size_t)(o + mi) * K;
      float4 v = *(const float4*)(ar + kc + c4 * 4);
      int k = c4 * 4;
      As[k][r] = v.x; As[k + 1][r] = v.y; As[k + 2][r] = v.z; As[k + 3][r] = v.w;
    }
#pragma unroll
    for (int i = 0; i < 4; ++i) {               // stage B: 64 rows x 64 k
      int f = tid + 256 * i;
      int r = f >> 4, c4 = f & 15;
      const float* br = Bb + (size_t)(n0 + r) * K + kc + c4 * 4;
      float4 v = *(const float4*)br;
      int k = c4 * 4;
      Bs[k][r] = v.x; Bs[k + 1][r] = v.y; Bs[k + 2][r] = v.z; Bs[k + 3][r] = v.w;
    }
    __syncthreads();
#pragma unroll 16
    for (int k = 0; k < 64; ++k) {
      float4 b = *(const float4*)&Bs[k][tn * 4];
#pragma unroll
      for (int g2 = 0; g2 < RG; ++g2) {
        float4 a = *(const float4*)&As[k][g2 * 64 + tm * 4];
        acc[g2*4+0][0] = fmaf(a.x, b.x, acc[g2*4+0][0]);
        acc[g2*4+0][1] = fmaf(a.x, b.y, acc[g2*4+0][1]);
        acc[g2*4+0][2] = fmaf(a.x, b.z, acc[g2*4+0][2]);
        acc[g2*4+0][3] = fmaf(a.x, b.w, acc[g2*4+0][3]);
        acc[g2*4+1][0] = fmaf(a.y, b.x, acc[g2*4+1][0]);
        acc[g2*4+1][1] = fmaf(a.y, b.y, acc[g2*4+1][1]);
        acc[g2*4+1][2] = fmaf(a.y, b.z, acc[g2*4+1][2]);
        acc[g2*4+1][3] = fmaf(a.y, b.w, acc[g2*4+1][3]);
        acc[g2*4+2][0] = fmaf(a.z, b.x, acc[g2*4+2][0]);
        acc[g2*4+2][1] = fmaf(a.z, b.y, acc[g2*4+2][1]);
        acc[g2*4+2][2] = fmaf(a.z, b.z, acc[g2*4+2][2]);
        acc[g2*4+2][3] = fmaf(a.z, b.w, acc[g2*4+2][3]);
        acc[g2*4+3][0] = fmaf(a.w, b.x, acc[g2*4+3][0]);
        acc[g2*4+3][1] = fmaf(a.w, b.y, acc[g2*4+3][1]);
        acc[g2*4+3][2] = fmaf(a.w, b.z, acc[g2*4+3][2]);
        acc[g2*4+3][3] = fmaf(a.w, b.w, acc[g2*4+3][3]);
      }
    }
    __syncthreads();
  }
  float4 bv = {0.f, 0.f, 0.f, 0.f};
  if constexpr (BI) bv = *(const float4*)(bias + n0 + tn * 4);
#pragma unroll
  for (int g2 = 0; g2 < RG; ++g2) {
#pragma unroll
    for (int i = 0; i < 4; ++i) {
      int row = m0 + g2 * 64 + tm * 4 + i;
      if (GR && row >= Mloc) continue;
      float* cr = C + (size_t)(o + row) * N + n0 + tn * 4;
      float r0 = acc[g2 * 4 + i][0], r1 = acc[g2 * 4 + i][1];
      float r2 = acc[g2 * 4 + i][2], r3 = acc[g2 * 4 + i][3];
      if constexpr (BI) { r0 += bv.x; r1 += bv.y; r2 += bv.z; r3 += bv.w; }
      if constexpr (SI) { r0 = nm_silu(r0); r1 = nm_silu(r1); r2 = nm_silu(r2); r3 = nm_silu(r3); }
      float4 st = {r0, r1, r2, r3};
      *(float4*)cr = st;
    }
  }
}

// ===================== bf16 MFMA GEMM (layer-3 MoE only) =====================
template<int F, int KK>
__global__ __launch_bounds__(256) void nm_bgemm(
    const unsigned short* __restrict__ A, const unsigned short* __restrict__ B,
    float* __restrict__ Cf, unsigned short* __restrict__ Cb,
    const float* __restrict__ bias, int M, int N,
    const int* __restrict__ list, const int* __restrict__ cnt,
    const int* __restrict__ off) {
  constexpr bool GA = F & 1, SI = F & 2, BI = F & 4, SB = F & 8, GR = F & 16;
  int wave = threadIdx.x >> 6, lane = threadIdx.x & 63;
  int n0 = blockIdx.x * 32;
  int m0 = blockIdx.y * 128 + wave * 32;
  int Mloc = M, o = 0;
  const unsigned short* Bb = B;
  if constexpr (GR) {
    int e = blockIdx.z;
    Mloc = cnt[e];
    o = off[e];
    Bb = B + (size_t)e * (size_t)N * KK;
  }
  if (m0 >= Mloc) return;                       // per-wave exit (no barriers)
  int lr = lane & 15, lk = (lane >> 4) * 8;
  const unsigned short* arow[2];
#pragma unroll
  for (int i = 0; i < 2; ++i) {
    int mi = m0 + i * 16 + lr;
    if (mi >= Mloc) mi = Mloc - 1;              // clamp (dup row, masked on store)
    int r = GA ? (list[o + mi] >> 1) : (o + mi);
    arow[i] = A + (size_t)r * KK;
  }
  const unsigned short* brow[2] = { Bb + (size_t)(n0 + lr) * KK,
                                    Bb + (size_t)(n0 + 16 + lr) * KK };
  f32x4 acc[2][2] = {};
#pragma unroll
  for (int ks = 0; ks < KK / 32; ++ks) {
    int kb = ks * 32 + lk;
    short8v a0 = *(const short8v*)(arow[0] + kb);
    short8v a1 = *(const short8v*)(arow[1] + kb);
    short8v b0 = *(const short8v*)(brow[0] + kb);
    short8v b1 = *(const short8v*)(brow[1] + kb);
    acc[0][0] = __builtin_amdgcn_mfma_f32_16x16x32_bf16(a0, b0, acc[0][0], 0, 0, 0);
    acc[0][1] = __builtin_amdgcn_mfma_f32_16x16x32_bf16(a0, b1, acc[0][1], 0, 0, 0);
    acc[1][0] = __builtin_amdgcn_mfma_f32_16x16x32_bf16(a1, b0, acc[1][0], 0, 0, 0);
    acc[1][1] = __builtin_amdgcn_mfma_f32_16x16x32_bf16(a1, b1, acc[1][1], 0, 0, 0);
  }
  float bc[2] = {0.f, 0.f};
  if constexpr (BI) {
    bc[0] = bias[n0 + (lane & 15)];
    bc[1] = bias[n0 + 16 + (lane & 15)];
  }
#pragma unroll
  for (int i = 0; i < 2; ++i) {
    int rbase = m0 + i * 16 + (lane >> 4) * 4;
#pragma unroll
    for (int r = 0; r < 4; ++r) {
      int row = rbase + r;
      if (GR && row >= Mloc) continue;
#pragma unroll
      for (int j = 0; j < 2; ++j) {
        float v = acc[i][j][r];
        if constexpr (BI) v += bc[j];
        if constexpr (SI) v = nm_silu(v);
        int col = n0 + j * 16 + (lane & 15);
        if constexpr (SB) Cb[(size_t)(o + row) * N + col] = nm_bf16r(v);
        else              Cf[(size_t)(o + row) * N + col] = v;
      }
    }
  }
}

// ========== fused out-proj + residual + LN2 + gate + ROUTE (last block) ==========
__global__ __launch_bounds__(256) void nm_oplng(
    const float* __restrict__ ao, const float* __restrict__ w,
    const float* __restrict__ bias, float* __restrict__ x,
    const float* __restrict__ g, const float* __restrict__ b,
    float* __restrict__ xl, unsigned short* __restrict__ xlb,
    const float* __restrict__ gw,
    int* __restrict__ topi, float* __restrict__ topw, int* __restrict__ cnt,
    int* __restrict__ ticket, int* __restrict__ off, int* __restrict__ list,
    int* __restrict__ posm) {
  __shared__ __align__(16) float As[64][36];
  __shared__ __align__(16) float Bs[64][132];
  __shared__ float Ls[32][9];
  __shared__ int doR;
  __shared__ int cv[NEXP], lcur[NEXP];
  int tid = threadIdx.x;
  int m0 = blockIdx.x * 32;
  int tm = tid >> 5, tn = tid & 31;
  float acc[4][4] = {};
  for (int kc = 0; kc < DD; kc += 64) {
#pragma unroll
    for (int i = 0; i < 2; ++i) {
      int ch = tid + 256 * i, r = ch >> 4, c4 = ch & 15;
      float4 v = *(const float4*)(ao + (size_t)(m0 + r) * DD + kc + c4 * 4);
      int k = c4 * 4;
      As[k][r] = v.x; As[k + 1][r] = v.y; As[k + 2][r] = v.z; As[k + 3][r] = v.w;
    }
#pragma unroll
    for (int i = 0; i < 8; ++i) {
      int ch = tid + 256 * i, r = ch >> 4, c4 = ch & 15;
      float4 v = *(const float4*)(w + (size_t)r * DD + kc + c4 * 4);
      int k = c4 * 4;
      Bs[k][r] = v.x; Bs[k + 1][r] = v.y; Bs[k + 2][r] = v.z; Bs[k + 3][r] = v.w;
    }
    __syncthreads();
#pragma unroll 8
    for (int k = 0; k < 64; ++k) {
      float4 a = *(const float4*)&As[k][tm * 4];
      float4 bb = *(const float4*)&Bs[k][tn * 4];
      acc[0][0] = fmaf(a.x, bb.x, acc[0][0]); acc[0][1] = fmaf(a.x, bb.y, acc[0][1]);
      acc[0][2] = fmaf(a.x, bb.z, acc[0][2]); acc[0][3] = fmaf(a.x, bb.w, acc[0][3]);
      acc[1][0] = fmaf(a.y, bb.x, acc[1][0]); acc[1][1] = fmaf(a.y, bb.y, acc[1][1]);
      acc[1][2] = fmaf(a.y, bb.z, acc[1][2]); acc[1][3] = fmaf(a.y, bb.w, acc[1][3]);
      acc[2][0] = fmaf(a.z, bb.x, acc[2][0]); acc[2][1] = fmaf(a.z, bb.y, acc[2][1]);
      acc[2][2] = fmaf(a.z, bb.z, acc[2][2]); acc[2][3] = fmaf(a.z, bb.w, acc[2][3]);
      acc[3][0] = fmaf(a.w, bb.x, acc[3][0]); acc[3][1] = fmaf(a.w, bb.y, acc[3][1]);
      acc[3][2] = fmaf(a.w, bb.z, acc[3][2]); acc[3][3] = fmaf(a.w, bb.w, acc[3][3]);
    }
    __syncthreads();
  }
  float4 bv = *(const float4*)(bias + tn * 4);
  float rr[4][4], s1[4], s2[4];
#pragma unroll
  for (int i = 0; i < 4; ++i) {
    int rw = m0 + tm * 4 + i;
    float4 xv = *(const float4*)(x + (size_t)rw * DD + tn * 4);
    float r0 = acc[i][0] + bv.x + xv.x;
    float r1 = acc[i][1] + bv.y + xv.y;
    float r2 = acc[i][2] + bv.z + xv.z;
    float r3 = acc[i][3] + bv.w + xv.w;
    rr[i][0] = r0; rr[i][1] = r1; rr[i][2] = r2; rr[i][3] = r3;
    float4 st = {r0, r1, r2, r3};
    *(float4*)(x + (size_t)rw * DD + tn * 4) = st;
    s1[i] = r0 + r1 + r2 + r3;
    s2[i] = r0 * r0 + r1 * r1 + r2 * r2 + r3 * r3;
  }
#pragma unroll
  for (int o = 16; o >= 1; o >>= 1) {
#pragma unroll
    for (int i = 0; i < 4; ++i) {
      s1[i] += __shfl_xor(s1[i], o, 64);
      s2[i] += __shfl_xor(s2[i], o, 64);
    }
  }
  float4 gv  = *(const float4*)(g + tn * 4);
  float4 bbv = *(const float4*)(b + tn * 4);
#pragma unroll
  for (int i = 0; i < 4; ++i) {
    int rw = m0 + tm * 4 + i;
    float mu = s1[i] * (1.f / 128.f);
    float var = s2[i] * (1.f / 128.f) - mu * mu;
    float rstd = rsqrtf(var + 1e-5f);
    float y0 = (rr[i][0] - mu) * rstd * gv.x + bbv.x;
    float y1 = (rr[i][1] - mu) * rstd * gv.y + bbv.y;
    float y2 = (rr[i][2] - mu) * rstd * gv.z + bbv.z;
    float y3 = (rr[i][3] - mu) * rstd * gv.w + bbv.w;
    float4 yv = {y0, y1, y2, y3};
    *(float4*)(xl + (size_t)rw * DD + tn * 4) = yv;
    if (xlb) {
      ushort4 us = {nm_bf16r(y0), nm_bf16r(y1), nm_bf16r(y2), nm_bf16r(y3)};
      *(ushort4*)(xlb + (size_t)rw * DD + tn * 4) = us;
    }
    *(float4*)&Bs[tm * 4 + i][tn * 4] = yv;     // stash for gate (f32)
  }
  __syncthreads();
  // gate: thread = (row, expert)
  int grow = tid >> 3, ge = tid & 7;
  const float4* xr = (const float4*)&Bs[grow][0];
  const float4* wr = (const float4*)(gw + (size_t)ge * DD);
  float sx = 0.f, sy = 0.f, sz = 0.f, sw = 0.f;
#pragma unroll
  for (int k2 = 0; k2 < 32; ++k2) {
    float4 a = xr[k2], w4 = wr[k2];
    sx = fmaf(a.x, w4.x, sx); sy = fmaf(a.y, w4.y, sy);
    sz = fmaf(a.z, w4.z, sz); sw = fmaf(a.w, w4.w, sw);
  }
  Ls[grow][ge] = (sx + sy) + (sz + sw);
  __syncthreads();
  if (ge == 0) {
    float gl[NEXP];
#pragma unroll
    for (int e = 0; e < NEXP; ++e) gl[e] = Ls[grow][e];
    int i0 = 0;
#pragma unroll
    for (int e = 1; e < NEXP; ++e) if (gl[e] > gl[i0]) i0 = e;
    int i1 = (i0 == 0) ? 1 : 0;
#pragma unroll
    for (int e = 0; e < NEXP; ++e) { if (e != i0 && gl[e] > gl[i1]) i1 = e; }
    float p1 = __expf(gl[i1] - gl[i0]);         // renormalized top-2 softmax
    float inv = 1.f / (1.f + p1);
    int n = m0 + grow;
    topi[2 * n] = i0; topi[2 * n + 1] = i1;
    topw[2 * n] = inv; topw[2 * n + 1] = p1 * inv;
    atomicAdd(cnt + i0, 1);
    atomicAdd(cnt + i1, 1);
  }
  // ---- fused routing: last-arriving block does prefix + scatter ----
  __syncthreads();
  if (tid == 0) {
    __threadfence();
    doR = (atomicAdd(ticket, 1) == 63);
    if (doR) __threadfence();
  }
  __syncthreads();
  if (doR) {
    if (tid < NEXP) cv[tid] = atomicAdd(cnt + tid, 0);
    __syncthreads();
    if (tid < NEXP) {
      int o2 = 0;
      for (int e = 0; e < tid; ++e) o2 += cv[e];
      lcur[tid] = o2;
      off[tid] = o2;
    }
    __syncthreads();
    for (int t = tid; t < 2 * NTOK; t += 256) {
      int e = topi[t];
      int p = atomicAdd(&lcur[e], 1);
      list[p] = t;
      posm[t] = p;
    }
  }
}

// ===================== attention v3: 512 blocks, swizzled K/V =====================
__global__ __launch_bounds__(256) void nm_attn3(const float* __restrict__ qkv,
                                                float* __restrict__ o) {
  __shared__ __align__(16) float smem[2 * SEQ * DHEAD];   // 64 KB
  float4* K4 = (float4*)smem;                   // [SEQ][8] swizzled chunks
  float4* V4 = (float4*)(smem + SEQ * DHEAD);
  int bh = blockIdx.x;
  int b = bh >> 2, h = bh & 3;
  int qt = blockIdx.y;
  int tid = threadIdx.x;
  const float* base = qkv + (size_t)b * SEQ * 384;
  for (int f = tid; f < SEQ * 8; f += 256) {
    int t = f >> 3, c4 = f & 7;
    int pc = (c4 + (t >> 4)) & 7;
    K4[t * 8 + pc] = *(const float4*)(base + (size_t)t * 384 + 128 + h * DHEAD + c4 * 4);
    V4[t * 8 + pc] = *(const float4*)(base + (size_t)t * 384 + 256 + h * DHEAD + c4 * 4);
  }
  __syncthreads();
  int qi = tid >> 4, slot = tid & 15;
  int tq = qt * 16 + qi;
  float qv[DHEAD];
  const float4* q4 = (const float4*)(base + (size_t)tq * 384 + h * DHEAD);
#pragma unroll
  for (int k = 0; k < 8; ++k) {
    float4 v = q4[k];
    qv[4*k] = v.x; qv[4*k+1] = v.y; qv[4*k+2] = v.z; qv[4*k+3] = v.w;
  }
  float m = -1e30f, s = 0.f, acc[DHEAD];
#pragma unroll
  for (int d = 0; d < DHEAD; ++d) acc[d] = 0.f;
  const float scale = 0.17677669529663687f;     // 1/sqrt(32)
  int sw = slot & 7;
  for (int jj = 0; jj < 16; ++jj) {
    int j = slot * 16 + jj;
    float sc = 0.f;
#pragma unroll
    for (int k = 0; k < 8; ++k) {
      float4 v = K4[j * 8 + ((k + sw) & 7)];
      sc += qv[4*k]*v.x + qv[4*k+1]*v.y + qv[4*k+2]*v.z + qv[4*k+3]*v.w;
    }
    sc *= scale;
    float mn = fmaxf(m, sc);
    float f = __expf(m - mn), p = __expf(sc - mn);
    s = s * f + p;
#pragma unroll
    for (int k = 0; k < 8; ++k) {
      float4 v = V4[j * 8 + ((k + sw) & 7)];
      acc[4*k]   = acc[4*k]  * f + p * v.x;
      acc[4*k+1] = acc[4*k+1]* f + p * v.y;
      acc[4*k+2] = acc[4*k+2]* f + p * v.z;
      acc[4*k+3] = acc[4*k+3]* f + p * v.w;
    }
    m = mn;
  }
  __syncthreads();                              // K/V consumed -> reuse as cbuf
  float* cb = smem;                             // [256][34]: 32 acc + m + s
  float* my = cb + (qi * 16 + slot) * 34;
#pragma unroll
  for (int d = 0; d < DHEAD; ++d) my[d] = acc[d];
  my[32] = m;
  my[33] = s;
  __syncthreads();
  int q2 = tid >> 4, dg = tid & 15;
  const float* qb = cb + q2 * 16 * 34;
  float M = qb[32];
#pragma unroll
  for (int t = 1; t < 16; ++t) M = fmaxf(M, qb[t * 34 + 32]);
  float S = 0.f, v0 = 0.f, v1 = 0.f;
#pragma unroll
  for (int t = 0; t < 16; ++t) {
    float w = __expf(qb[t * 34 + 32] - M);
    S += qb[t * 34 + 33] * w;
    v0 += w * qb[t * 34 + dg * 2];
    v1 += w * qb[t * 34 + dg * 2 + 1];
  }
  float inv = 1.f / S;
  float* orow = o + (size_t)(b * SEQ + qt * 16 + q2) * DD + h * DHEAD + dg * 2;
  orow[0] = v0 * inv;
  orow[1] = v1 * inv;
}

// ===================== fallback-only kernels =====================
__global__ void nm_qkv(const float* __restrict__ xl, const float* __restrict__ w,
                       const float* __restrict__ bias, float* __restrict__ qkv) {
  __shared__ __align__(16) float xs[DD];
  int n = blockIdx.x, tid = threadIdx.x;        // block = 128
  xs[tid] = xl[n * DD + tid];
  __syncthreads();
#pragma unroll
  for (int jj = 0; jj < 3; ++jj) {
    int j = tid + jj * 128;
    qkv[(size_t)n * 384 + j] = nm_dotv<32>(xs, w + (size_t)j * DD) + bias[j];
  }
}

__global__ void nm_outproj(const float* __restrict__ ao, const float* __restrict__ w,
                           const float* __restrict__ bias, float* __restrict__ x) {
  __shared__ __align__(16) float os[DD];
  int n = blockIdx.x, tid = threadIdx.x;        // block = 128
  os[tid] = ao[n * DD + tid];
  __syncthreads();
  x[n * DD + tid] += nm_dotv<32>(os, w + (size_t)tid * DD) + bias[tid];
}

__global__ void nm_moe(const float* __restrict__ x2, const float* __restrict__ gw,
                       const float* __restrict__ w1, const float* __restrict__ w2,
                       float* __restrict__ x) {
  __shared__ __align__(16) float xs[DD];
  __shared__ __align__(16) float hs[DHID];
  __shared__ float gl[NEXP];
  __shared__ int   ei[2];
  __shared__ float ew[2];
  int n = blockIdx.x, tid = threadIdx.x;        // block = 256
  if (tid < DD) xs[tid] = x2[n * DD + tid];
  __syncthreads();
  if (tid < NEXP) gl[tid] = nm_dotv<32>(xs, gw + (size_t)tid * DD);
  __syncthreads();
  if (tid == 0) {
    int i0 = 0;
#pragma unroll
    for (int e = 1; e < NEXP; ++e) if (gl[e] > gl[i0]) i0 = e;
    int i1 = (i0 == 0) ? 1 : 0;
    for (int e = 0; e < NEXP; ++e) { if (e == i0) continue; if (gl[e] > gl[i1]) i1 = e; }
    float p1 = __expf(gl[i1] - gl[i0]);
    float inv = 1.f / (1.f + p1);
    ei[0] = i0; ei[1] = i1; ew[0] = inv; ew[1] = p1 * inv;
  }
  __syncthreads();
  float yacc = 0.f;
  for (int t2 = 0; t2 < 2; ++t2) {
    int e = ei[t2];
    float wt = ew[t2];
    const float* w1e = w1 + (size_t)e * DHID * DD;
#pragma unroll
    for (int jj = 0; jj < 2; ++jj) {
      int j = tid + jj * 256;
      float a = nm_dotv<32>(xs, w1e + (size_t)j * DD);
      hs[j] = nm_silu(a);
    }
    __syncthreads();
    if (tid < DD) yacc += wt * nm_dotv<128>(hs, w2 + ((size_t)e * DD + tid) * DHID);
    __syncthreads();
  }
  if (tid < DD) x[n * DD + tid] += yacc;
}

__device__ __forceinline__ short8v nm_cvt8(const float* p) {
  const float4* p4 = (const float4*)p;
  float4 a = p4[0], b = p4[1];
  short8v r;
  r[0] = (short)nm_bf16r(a.x); r[1] = (short)nm_bf16r(a.y);
  r[2] = (short)nm_bf16r(a.z); r[3] = (short)nm_bf16r(a.w);
  r[4] = (short)nm_bf16r(b.x); r[5] = (short)nm_bf16r(b.y);
  r[6] = (short)nm_bf16r(b.z); r[7] = (short)nm_bf16r(b.w);
  return r;
}

__global__ __launch_bounds__(256) void nm_lmhead_f32(
    const float* __restrict__ xf, const float* __restrict__ lmw,
    float* __restrict__ out) {
  int wave = threadIdx.x >> 6, lane = threadIdx.x & 63;
  int wr = wave >> 1, wc = wave & 1;
  int row0 = blockIdx.y * 128 + wr * 64;
  int col0 = blockIdx.x * 128 + wc * 64;
  int lr = lane & 15, lk = (lane >> 4) * 8;
  f32x4 acc[4][4] = {};
#pragma unroll
  for (int ks = 0; ks < 4; ++ks) {
    int kb = ks * 32 + lk;
    short8v a[4], b[4];
#pragma unroll
    for (int i = 0; i < 4; ++i)
      a[i] = nm_cvt8(xf + (size_t)(row0 + i * 16 + lr) * DD + kb);
#pragma unroll
    for (int j = 0; j < 4; ++j) {
      int c = col0 + j * 16 + lr;
      if (c < NVOCAB) b[j] = nm_cvt8(lmw + (size_t)c * DD + kb);
      else {
        short8v z;
#pragma unroll
        for (int e = 0; e < 8; ++e) z[e] = 0;
        b[j] = z;
      }
    }
#pragma unroll
    for (int i = 0; i < 4; ++i)
#pragma unroll
      for (int j = 0; j < 4; ++j)
        acc[i][j] = __builtin_amdgcn_mfma_f32_16x16x32_bf16(a[i], b[j], acc[i][j], 0, 0, 0);
  }
  int cr = (lane >> 4) * 4;
#pragma unroll
  for (int j = 0; j < 4; ++j) {
    int c = col0 + j * 16 + (lane & 15);
    if (c < NVOCAB) {
#pragma unroll
      for (int i = 0; i < 4; ++i)
#pragma unroll
        for (int r = 0; r < 4; ++r)
          out[(size_t)(row0 + i * 16 + cr + r) * NVOCAB + c] = acc[i][j][r];
    }
  }
}

// ===== LM head (bf16, LDS-staged, coalesced epilogue). grid (rows=16, cols=393):
// consecutive blocks share the same B col-tile -> lmwb read ~once into L2.
__global__ __launch_bounds__(256) void nm_lmhead2(
    const unsigned short* __restrict__ xfb, const unsigned short* __restrict__ lmwb,
    float* __restrict__ out) {
  __shared__ __align__(16) unsigned char smem[132 * 128 * 4];  // 67.5 KB
  unsigned short* Ab = (unsigned short*)smem;
  unsigned short* Bb = Ab + 128 * 128;
  int tid = threadIdx.x;
  int row0 = blockIdx.x * 128, col0 = blockIdx.y * 128;
#pragma unroll
  for (int i = 0; i < 8; ++i) {
    int ch = tid + i * 256;
    int r = ch >> 4, s = ch & 15;
    int sg = s ^ (r & 7);                       // swizzled source slot
    *(short8v*)&Ab[r * 128 + s * 8] =
        *(const short8v*)(xfb + (size_t)(row0 + r) * DD + sg * 8);
    *(short8v*)&Bb[r * 128 + s * 8] =
        *(const short8v*)(lmwb + (size_t)(col0 + r) * DD + sg * 8);
  }
  __syncthreads();
  int wave = tid >> 6, lane = tid & 63;
  int wr = wave >> 1, wc = wave & 1;
  int lr = lane & 15, hk = lane >> 4;
  f32x4 acc[4][4] = {};
#pragma unroll
  for (int ks = 0; ks < 4; ++ks) {
    int sg = ks * 4 + hk;
    int sx = (sg ^ (lr & 7)) * 8;
    short8v a[4], b[4];
#pragma unroll
    for (int i = 0; i < 4; ++i)
      a[i] = *(const short8v*)&Ab[(wr * 64 + i * 16 + lr) * 128 + sx];
#pragma unroll
    for (int j = 0; j < 4; ++j)
      b[j] = *(const short8v*)&Bb[(wc * 64 + j * 16 + lr) * 128 + sx];
#pragma unroll
    for (int i = 0; i < 4; ++i)
#pragma unroll
      for (int j = 0; j < 4; ++j)
        acc[i][j] = __builtin_amdgcn_mfma_f32_16x16x32_bf16(a[i], b[j], acc[i][j], 0, 0, 0);
  }
  __syncthreads();
  float* Cs = (float*)smem;
  int hi4 = hk * 4;
#pragma unroll
  for (int j = 0; j < 4; ++j)
#pragma unroll
    for (int i = 0; i < 4; ++i)
#pragma unroll
      for (int r = 0; r < 4; ++r)
        Cs[(wr * 64 + i * 16 + hi4 + r) * 132 + wc * 64 + j * 16 + lr] = acc[i][j][r];
  __syncthreads();
  bool full = (col0 + 128 <= NVOCAB);
#pragma unroll 4
  for (int rr = 0; rr < 32; ++rr) {
    int row = wave * 32 + rr;
    float v0 = Cs[row * 132 + lane];
    float v1 = Cs[row * 132 + 64 + lane];
    size_t base = (size_t)(row0 + row) * NVOCAB + col0;
    if (full) {
      out[base + lane] = v0;
      out[base + 64 + lane] = v1;
    } else {
      if (col0 + lane < NVOCAB)      out[base + lane] = v0;
      if (col0 + 64 + lane < NVOCAB) out[base + 64 + lane] = v1;
    }
  }
}

extern "C" void kernel_launch(void* const* d_in, const int* in_sizes, int n_in,
                              void* d_out, int out_size, void* d_ws, size_t ws_size,
                              hipStream_t stream) {
  const int*   idx   = (const int*)  d_in[0];
  const float* tok   = (const float*)d_in[1];
  const float* pos   = (const float*)d_in[2];
  const float* ln1g  = (const float*)d_in[3];
  const float* ln1b  = (const float*)d_in[4];
  const float* inw   = (const float*)d_in[5];
  const float* inb   = (const float*)d_in[6];
  const float* outw  = (const float*)d_in[7];
  const float* outb  = (const float*)d_in[8];
  const float* ln2g  = (const float*)d_in[9];
  const float* ln2b  = (const float*)d_in[10];
  const float* gatew = (const float*)d_in[11];
  const float* w1    = (const float*)d_in[12];
  const float* w2    = (const float*)d_in[13];
  const float* lnfg  = (const float*)d_in[14];
  const float* lnfb  = (const float*)d_in[15];
  const float* lmw   = (const float*)d_in[16];
  float* out = (float*)d_out;

  float* ws   = (float*)d_ws;
  float* x    = ws;                              // 262144 f32
  float* xl   = x    + NTOK * DD;                // 262144
  float* qkv  = xl   + NTOK * DD;                // 786432
  float* ao   = qkv  + NTOK * 384;               // 262144
  float* topw = ao   + NTOK * DD;                // 4096
  float* H    = topw + 2 * NTOK;                 // 2097152 (f32, layers 0-2)
  float* yb   = H    + 2 * NTOK * DHID;          // 524288
  int*   topi = (int*)(yb + 2 * NTOK * DD);      // 4096
  int*   list = topi + 2 * NTOK;
  int*   posm = list + 2 * NTOK;
  int*   cnt  = posm + 2 * NTOK;                 // 32
  int*   offs = cnt  + NLAYER * NEXP;            // 32
  int*   tick = offs + NLAYER * NEXP;            // 8
  unsigned short* xlb  = (unsigned short*)(tick + 8);      // 262144
  unsigned short* Hb   = xlb + NTOK * DD;        // 2097152 (bf16, layer 3)
  unsigned short* xfb  = Hb  + 2 * NTOK * DHID;  // 262144
  unsigned short* w1b3 = xfb + NTOK * DD;        // 524288
  unsigned short* w2b3 = w1b3 + NEXP * DHID * DD;  // 524288
  unsigned short* lmwb = w2b3 + NEXP * DD * DHID;  // 6438912
  const size_t need = (size_t)((char*)(lmwb + (size_t)VPAD * DD) - (char*)d_ws);
  const bool pre = (ws_size >= need);

  const float* w1l3 = w1 + (size_t)3 * NEXP * DHID * DD;
  const float* w2l3 = w2 + (size_t)3 * NEXP * DD * DHID;

  if (pre) {
    nm_init<<<CVTB + NTOK / 4 + 1, 256, 0, stream>>>(
        idx, tok, pos, ln1g, ln1b, lmw, w1l3, w2l3, x, xl, lmwb, w1b3, w2b3, cnt);
    for (int l = 0; l < NLAYER; ++l) {
      // QKV (f32): [2048,384] = xl @ in_w^T + b   (MT=64 -> 192 blocks)
      nm_gemm2<4, 64><<<dim3(384 / 64, NTOK / 64), 256, 0, stream>>>(
          xl, inw + (size_t)l * 384 * DD, qkv, inb + (size_t)l * 384,
          NTOK, 384, DD, nullptr, nullptr, nullptr);
      nm_attn3<<<dim3(NBATCH * NHEAD, SEQ / 16), 256, 0, stream>>>(qkv, ao);
      // fused out-proj + residual + LN2 + gate + route (last block)
      nm_oplng<<<NTOK / 32, 256, 0, stream>>>(
          ao, outw + (size_t)l * DD * DD, outb + (size_t)l * DD, x,
          ln2g + l * DD, ln2b + l * DD, xl, (l == 3) ? xlb : (unsigned short*)nullptr,
          gatew + (size_t)l * NEXP * DD, topi, topw, cnt + l * NEXP,
          tick + l, offs + l * NEXP, list, posm);
      int* cnt_l = cnt + l * NEXP;
      int* off_l = offs + l * NEXP;
      if (l < 3) {
        // f32 grouped expert GEMMs (routing-safe), MT=64 for parallelism
        const float* w1l = w1 + (size_t)l * NEXP * DHID * DD;
        const float* w2l = w2 + (size_t)l * NEXP * DD * DHID;
        nm_gemm2<19, 64><<<dim3(DHID / 64, 2 * NTOK / 64, NEXP), 256, 0, stream>>>(
            xl, w1l, H, nullptr, 0, DHID, DD, list, cnt_l, off_l);
        nm_gemm2<16, 64><<<dim3(DD / 64, 2 * NTOK / 64, NEXP), 256, 0, stream>>>(
            H, w2l, yb, nullptr, 0, DD, DHID, nullptr, cnt_l, off_l);
      } else {
        // layer-3 MoE: bf16 MFMA (no routing downstream -> safe)
        nm_bgemm<27, 128><<<dim3(DHID / 32, 32, NEXP), 256, 0, stream>>>(
            xlb, w1b3, nullptr, Hb, nullptr, 0, DHID, list, cnt_l, off_l);
        nm_bgemm<16, 512><<<dim3(DD / 32, 32, NEXP), 256, 0, stream>>>(
            Hb, w2b3, yb, nullptr, nullptr, 0, DD, nullptr, cnt_l, off_l);
      }
      const float* gN = (l < NLAYER - 1) ? ln1g + (l + 1) * DD : lnfg;
      const float* bN = (l < NLAYER - 1) ? ln1b + (l + 1) * DD : lnfb;
      nm_combine_ln<<<NTOK, 64, 0, stream>>>(
          yb, posm, topw, x, gN, bN, xl,
          (l == NLAYER - 1) ? xfb : (unsigned short*)nullptr);
    }
    nm_lmhead2<<<dim3(NTOK / 128, VPAD / 128), 256, 0, stream>>>(xfb, lmwb, out);
  } else {
    // compact fallback: per-token f32 path
    nm_embed_ln<<<NTOK, 64, 0, stream>>>(idx, tok, pos, ln1g, ln1b, x, xl);
    for (int l = 0; l < NLAYER; ++l) {
      nm_qkv<<<NTOK, 128, 0, stream>>>(xl, inw + (size_t)l * 384 * DD,
                                       inb + (size_t)l * 384, qkv);
      nm_attn3<<<dim3(NBATCH * NHEAD, SEQ / 16), 256, 0, stream>>>(qkv, ao);
      nm_outproj<<<NTOK, 128, 0, stream>>>(ao, outw + (size_t)l * DD * DD,
                                           outb + (size_t)l * DD, x);
      nm_ln<<<NTOK, 64, 0, stream>>>(x, ln2g + l * DD, ln2b + l * DD, xl);
      nm_moe<<<NTOK, 256, 0, stream>>>(xl, gatew + (size_t)l * NEXP * DD,
                                       w1 + (size_t)l * NEXP * DHID * DD,
                                       w2 + (size_t)l * NEXP * DD * DHID, x);
      const float* gN = (l < NLAYER - 1) ? ln1g + (l + 1) * DD : lnfg;
      const float* bN = (l < NLAYER - 1) ? ln1b + (l + 1) * DD : lnfb;
      nm_ln<<<NTOK, 64, 0, stream>>>(x, gN, bN, xl);
    }
    nm_lmhead_f32<<<dim3(VPAD / 128, NTOK / 128), 256, 0, stream>>>(xl, lmw, out);
  }
}